// Round 1
// baseline (79.703 us; speedup 1.0000x reference)
//
#include <hip/hip_runtime.h>

// Reference analysis: the model returns
//   softmax(h @ w_lin.T + b_lin, axis=-1)  with output shape [SEQ, B, 1].
// Softmax over a size-1 axis is identically 1.0 for any finite input, so the
// encoder LSTM, decoder LSTM, and linear head are all dead code w.r.t. the
// output. The exact reference output is ones((128, 256, 1), float32).
// Optimal kernel: vectorized constant fill of d_out with 1.0f.

__global__ void fill_ones_f4(float4* __restrict__ out, int n4) {
    int i = blockIdx.x * blockDim.x + threadIdx.x;
    if (i < n4) {
        out[i] = make_float4(1.0f, 1.0f, 1.0f, 1.0f);
    }
}

__global__ void fill_ones_tail(float* __restrict__ out, int start, int n) {
    int i = start + blockIdx.x * blockDim.x + threadIdx.x;
    if (i < n) {
        out[i] = 1.0f;
    }
}

extern "C" void kernel_launch(void* const* d_in, const int* in_sizes, int n_in,
                              void* d_out, int out_size, void* d_ws, size_t ws_size,
                              hipStream_t stream) {
    float* out = (float*)d_out;

    int n4 = out_size / 4;            // out_size = 32768 -> 8192 float4 stores
    int tail_start = n4 * 4;

    if (n4 > 0) {
        const int threads = 256;
        int blocks = (n4 + threads - 1) / threads;   // 32 blocks
        fill_ones_f4<<<blocks, threads, 0, stream>>>((float4*)out, n4);
    }
    if (tail_start < out_size) {      // not taken for 32768, kept for generality
        const int threads = 64;
        int rem = out_size - tail_start;
        int blocks = (rem + threads - 1) / threads;
        fill_ones_tail<<<blocks, threads, 0, stream>>>(out, tail_start, out_size);
    }
}